// Round 1
// baseline (2809.747 us; speedup 1.0000x reference)
//
#include <hip/hip_runtime.h>

#define CDIM 64
#define SLOPE 0.2f

// ---------------------------------------------------------------------------
// Y = X @ W   (X: [n,64], W: [64,64]); also pL = Y @ a[0:64], pR = Y @ a[64:128]
// One wave (64 lanes) per row; W and a staged in LDS.
// ---------------------------------------------------------------------------
__global__ void gemm64_kernel(const float* __restrict__ X, const float* __restrict__ W,
                              const float* __restrict__ a, float* __restrict__ Y,
                              float* __restrict__ pL, float* __restrict__ pR, int n)
{
    __shared__ float sW[64 * 64];
    __shared__ float sa[128];
    int tid = threadIdx.x;
    for (int k = tid; k < 64 * 64; k += blockDim.x) sW[k] = W[k];
    if (tid < 128) sa[tid] = a[tid];
    __syncthreads();

    const int lane = tid & 63;
    const int gwave = (int)((blockIdx.x * blockDim.x + tid) >> 6);
    const int nwaves = (int)((gridDim.x * blockDim.x) >> 6);

    for (int r = gwave; r < n; r += nwaves) {
        float x = X[(size_t)r * 64 + lane];
        float acc = 0.f;
#pragma unroll
        for (int k = 0; k < 64; ++k) {
            acc = fmaf(__shfl(x, k, 64), sW[k * 64 + lane], acc);
        }
        Y[(size_t)r * 64 + lane] = acc;
        float l = acc * sa[lane];
        float rr = acc * sa[64 + lane];
#pragma unroll
        for (int off = 32; off; off >>= 1) {
            l += __shfl_xor(l, off, 64);
            rr += __shfl_xor(rr, off, 64);
        }
        if (lane == 0) { pL[r] = l; pR[r] = rr; }
    }
}

// ---------------------------------------------------------------------------
// HBS edge scores: e = leakyrelu(pL[i] + pR[j]); den[i] += e   (f64 accum)
// idx layout: [2,E] row-major -> i = idx[k], j = idx[E+k]
// ---------------------------------------------------------------------------
__global__ void edge_score_hbs(const int* __restrict__ idx, const float* __restrict__ pL,
                               const float* __restrict__ pR, float* __restrict__ e,
                               double* __restrict__ den, int E)
{
    int k = blockIdx.x * blockDim.x + threadIdx.x;
    if (k >= E) return;
    int i = idx[k];
    int j = idx[E + k];
    float v = pL[i] + pR[j];
    v = v > 0.f ? v : SLOPE * v;
    e[k] = v;
    atomicAdd(&den[i], (double)v);
}

// HBNS edge scores: e = leakyrelu(pS[s] + pT[t]); denT[t] += e; denS[s] += e
__global__ void edge_score_hbns(const int* __restrict__ tIdx, const int* __restrict__ sIdx,
                                const float* __restrict__ pS, const float* __restrict__ pT,
                                float* __restrict__ e, double* __restrict__ denT,
                                double* __restrict__ denS, int E)
{
    int k = blockIdx.x * blockDim.x + threadIdx.x;
    if (k >= E) return;
    int t = tIdx[k];
    int s = sIdx[k];
    float v = pS[s] + pT[t];
    v = v > 0.f ? v : SLOPE * v;
    e[k] = v;
    atomicAdd(&denT[t], (double)v);
    atomicAdd(&denS[s], (double)v);
}

// ---------------------------------------------------------------------------
// Scatter: out[ii[k]] += (e[k]/den[ii[k]]) * M[jj[k]]   (64 channels)
// 16 lanes per edge, float4 gather, 4 scalar f32 atomics per lane.
// ---------------------------------------------------------------------------
__global__ void edge_scatter(const int* __restrict__ ii, const int* __restrict__ jj,
                             const float* __restrict__ e, const double* __restrict__ den,
                             const float* __restrict__ M, float* __restrict__ out, int E)
{
    long long tid = (long long)blockIdx.x * blockDim.x + threadIdx.x;
    int k = (int)(tid >> 4);
    if (k >= E) return;
    int l = (int)(tid & 15);
    int i = ii[k];
    int j = jj[k];
    double d = den[i];
    float df = (d == 0.0) ? 1.f : (float)d;
    float att = e[k] / df;
    const float4 v = *reinterpret_cast<const float4*>(M + (size_t)j * 64 + l * 4);
    float* o = out + (size_t)i * 64 + l * 4;
    atomicAdd(o + 0, att * v.x);
    atomicAdd(o + 1, att * v.y);
    atomicAdd(o + 2, att * v.z);
    atomicAdd(o + 3, att * v.w);
}

extern "C" void kernel_launch(void* const* d_in, const int* in_sizes, int n_in,
                              void* d_out, int out_size, void* d_ws, size_t ws_size,
                              hipStream_t stream)
{
    const float* x0  = (const float*)d_in[0];
    const float* x1  = (const float*)d_in[1];
    const float* x2  = (const float*)d_in[2];
    const float* x3  = (const float*)d_in[3];
    const float* x4  = (const float*)d_in[4];
    const int*   adj0 = (const int*)d_in[5];
    const int*   adj1 = (const int*)d_in[6];
    const int*   inct = (const int*)d_in[7];
    const int*   incs = (const int*)d_in[8];
    const float* W0  = (const float*)d_in[9];
    const float* a0  = (const float*)d_in[10];
    const float* W1  = (const float*)d_in[11];
    const float* a1  = (const float*)d_in[12];
    const float* Ws  = (const float*)d_in[13];
    const float* Wt  = (const float*)d_in[14];
    const float* ans = (const float*)d_in[15];

    const int N0  = in_sizes[0] / CDIM;      // 50000
    const int N1  = in_sizes[1] / CDIM;      // 100000
    const int NP  = in_sizes[2];             // passthrough flat sizes (20000*64)
    const int E0  = in_sizes[5] / 2;         // 800000
    const int E1  = in_sizes[6] / 2;         // 1600000
    const int E01 = in_sizes[7];             // 200000

    float* out0 = (float*)d_out;                    // x_0_level1 [N0*64]
    float* out1 = out0 + (size_t)N0 * CDIM;         // x_1_level1 [N1*64]
    float* outp = out1 + (size_t)N1 * CDIM;         // x_2, x_3, x_4

    // ---- workspace layout (doubles first for alignment) ----
    char* w = (char*)d_ws;
    size_t off = 0;
    double* den0 = (double*)(w + off); off += (size_t)N0 * 8;
    double* den1 = (double*)(w + off); off += (size_t)N1 * 8;
    double* denT = (double*)(w + off); off += (size_t)N0 * 8;
    double* denS = (double*)(w + off); off += (size_t)N1 * 8;
    size_t denBytes = off;                            // contiguous den region
    float* m0  = (float*)(w + off); off += (size_t)N0 * CDIM * 4;
    float* m1  = (float*)(w + off); off += (size_t)N1 * CDIM * 4;
    float* sm  = (float*)(w + off); off += (size_t)N1 * CDIM * 4;
    float* tm  = (float*)(w + off); off += (size_t)N0 * CDIM * 4;
    float* pl0 = (float*)(w + off); off += (size_t)N0 * 4;
    float* pr0 = (float*)(w + off); off += (size_t)N0 * 4;
    float* pl1 = (float*)(w + off); off += (size_t)N1 * 4;
    float* pr1 = (float*)(w + off); off += (size_t)N1 * 4;
    float* pls = (float*)(w + off); off += (size_t)N1 * 4;   // p_s  (sm @ a_ns[:C])
    float* prs = (float*)(w + off); off += (size_t)N1 * 4;   // unused half
    float* plt = (float*)(w + off); off += (size_t)N0 * 4;   // unused half
    float* prt = (float*)(w + off); off += (size_t)N0 * 4;   // p_t  (tm @ a_ns[C:])
    float* e0  = (float*)(w + off); off += (size_t)E0 * 4;
    float* e1  = (float*)(w + off); off += (size_t)E1 * 4;
    float* e01 = (float*)(w + off); off += (size_t)E01 * 4;
    (void)ws_size; (void)n_in; (void)out_size;

    // ---- zero accumulators ----
    hipMemsetAsync(den0, 0, denBytes, stream);
    hipMemsetAsync(out0, 0, ((size_t)N0 + N1) * CDIM * sizeof(float), stream);

    // ---- dense projections ----
    dim3 blk(256);
    gemm64_kernel<<<1024, blk, 0, stream>>>(x0, W0, a0, m0, pl0, pr0, N0);
    gemm64_kernel<<<1024, blk, 0, stream>>>(x1, W1, a1, m1, pl1, pr1, N1);
    gemm64_kernel<<<1024, blk, 0, stream>>>(x1, Ws, ans, sm, pls, prs, N1);
    gemm64_kernel<<<1024, blk, 0, stream>>>(x0, Wt, ans, tm, plt, prt, N0);

    // ---- edge scores + denominators ----
    edge_score_hbs<<<(E0 + 255) / 256, blk, 0, stream>>>(adj0, pl0, pr0, e0, den0, E0);
    edge_score_hbs<<<(E1 + 255) / 256, blk, 0, stream>>>(adj1, pl1, pr1, e1, den1, E1);
    edge_score_hbns<<<(E01 + 255) / 256, blk, 0, stream>>>(inct, incs, pls, prt, e01, denT, denS, E01);

    // ---- attention-weighted scatter ----
    long long t0 = (long long)E0 * 16, t1 = (long long)E1 * 16, t01 = (long long)E01 * 16;
    edge_scatter<<<(int)((t0 + 255) / 256), blk, 0, stream>>>(adj0, adj0 + E0, e0, den0, m0, out0, E0);
    edge_scatter<<<(int)((t1 + 255) / 256), blk, 0, stream>>>(adj1, adj1 + E1, e1, den1, m1, out1, E1);
    edge_scatter<<<(int)((t01 + 255) / 256), blk, 0, stream>>>(inct, incs, e01, denT, sm, out0, E01);
    edge_scatter<<<(int)((t01 + 255) / 256), blk, 0, stream>>>(incs, inct, e01, denS, tm, out1, E01);

    // ---- passthroughs x_2, x_3, x_4 ----
    hipMemcpyAsync(outp,          x2, (size_t)NP * sizeof(float), hipMemcpyDeviceToDevice, stream);
    hipMemcpyAsync(outp + NP,     x3, (size_t)NP * sizeof(float), hipMemcpyDeviceToDevice, stream);
    hipMemcpyAsync(outp + 2 * NP, x4, (size_t)NP * sizeof(float), hipMemcpyDeviceToDevice, stream);
}

// Round 2
// 1234.814 us; speedup vs baseline: 2.2754x; 2.2754x over previous
//
#include <hip/hip_runtime.h>

#define CDIM 64
#define SLOPE 0.2f

// ---------------------------------------------------------------------------
// Y = X @ W   (X: [n,64], W: [64,64]); also pL = Y @ a[0:64], pR = Y @ a[64:128]
// One wave (64 lanes) per row; W and a staged in LDS.
// ---------------------------------------------------------------------------
__global__ void gemm64_kernel(const float* __restrict__ X, const float* __restrict__ W,
                              const float* __restrict__ a, float* __restrict__ Y,
                              float* __restrict__ pL, float* __restrict__ pR, int n)
{
    __shared__ float sW[64 * 64];
    __shared__ float sa[128];
    int tid = threadIdx.x;
    for (int k = tid; k < 64 * 64; k += blockDim.x) sW[k] = W[k];
    if (tid < 128) sa[tid] = a[tid];
    __syncthreads();

    const int lane = tid & 63;
    const int gwave = (int)((blockIdx.x * blockDim.x + tid) >> 6);
    const int nwaves = (int)((gridDim.x * blockDim.x) >> 6);

    for (int r = gwave; r < n; r += nwaves) {
        float x = X[(size_t)r * 64 + lane];
        float acc = 0.f;
#pragma unroll
        for (int k = 0; k < 64; ++k) {
            acc = fmaf(__shfl(x, k, 64), sW[k * 64 + lane], acc);
        }
        Y[(size_t)r * 64 + lane] = acc;
        float l = acc * sa[lane];
        float rr = acc * sa[64 + lane];
#pragma unroll
        for (int off = 32; off; off >>= 1) {
            l += __shfl_xor(l, off, 64);
            rr += __shfl_xor(rr, off, 64);
        }
        if (lane == 0) { pL[r] = l; pR[r] = rr; }
    }
}

// ---------------------------------------------------------------------------
// Histogram of edge targets into cnt[] (int atomics).
// ---------------------------------------------------------------------------
__global__ void count_kernel(const int* __restrict__ keys, int* __restrict__ cnt, int E)
{
    int k = blockIdx.x * blockDim.x + threadIdx.x;
    if (k >= E) return;
    atomicAdd(&cnt[keys[k]], 1);
}

// ---------------------------------------------------------------------------
// Single-block exclusive scan: cnt[] (counts) -> cnt[] (row start offsets).
// After fill, cnt[i] becomes row END of row i (start = cnt[i-1], or 0).
// ---------------------------------------------------------------------------
__global__ void scan_kernel(int* __restrict__ cnt, int n)
{
    __shared__ int part[1024];
    int t = threadIdx.x;
    int chunk = (n + 1023) >> 10;
    int lo = t * chunk, hi = min(lo + chunk, n);
    int s = 0;
    for (int i = lo; i < hi; ++i) s += cnt[i];
    part[t] = s;
    __syncthreads();
    for (int off = 1; off < 1024; off <<= 1) {
        int v = (t >= off) ? part[t - off] : 0;
        __syncthreads();
        part[t] += v;
        __syncthreads();
    }
    int base = (t == 0) ? 0 : part[t - 1];
    for (int i = lo; i < hi; ++i) {
        int c = cnt[i];
        cnt[i] = base;
        base += c;
    }
}

// ---------------------------------------------------------------------------
// CSR fill: e = leakyrelu(pA[key] + pB[val]); csr[pos] = (val, e)
// pos = atomicAdd(cursor[key]) — cursor holds row-start offsets from scan.
// ---------------------------------------------------------------------------
__global__ void fill_kernel(const int* __restrict__ keys, const int* __restrict__ vals,
                            const float* __restrict__ pA, const float* __restrict__ pB,
                            int* __restrict__ cursor, int2* __restrict__ csr, int E)
{
    int k = blockIdx.x * blockDim.x + threadIdx.x;
    if (k >= E) return;
    int i = keys[k];
    int j = vals[k];
    float v = pA[i] + pB[j];
    v = v > 0.f ? v : SLOPE * v;
    int pos = atomicAdd(&cursor[i], 1);
    csr[pos] = make_int2(j, __float_as_int(v));
}

// ---------------------------------------------------------------------------
// Pull gather: one wave per row r. out[r] (+)= (1/den) * sum_e e * M[j]
// cursor[r] = row end (post-fill); row start = cursor[r-1] (or 0).
// ---------------------------------------------------------------------------
template <int ACCUM>
__global__ void gather_kernel(const int* __restrict__ cursor, const int2* __restrict__ csr,
                              const float* __restrict__ M, float* __restrict__ out, int n)
{
    const int lane = threadIdx.x & 63;
    int wave = (int)((blockIdx.x * blockDim.x + threadIdx.x) >> 6);
    int nw = (int)((gridDim.x * blockDim.x) >> 6);
    for (int r = wave; r < n; r += nw) {
        int p0 = (r == 0) ? 0 : cursor[r - 1];
        int p1 = cursor[r];
        float acc = 0.f, se = 0.f;
        for (int p = p0; p < p1; p += 64) {
            int q = p + lane;
            int2 je = (q < p1) ? csr[q] : make_int2(0, 0);
            float ef = (q < p1) ? __int_as_float(je.y) : 0.f;
            se += ef;
            int cnt = min(64, p1 - p);
            for (int t = 0; t < cnt; ++t) {
                int jj = __shfl(je.x, t, 64);
                float ee = __shfl(ef, t, 64);
                acc = fmaf(ee, M[(size_t)jj * 64 + lane], acc);
            }
        }
#pragma unroll
        for (int off = 32; off; off >>= 1) se += __shfl_xor(se, off, 64);
        float den = (se == 0.f) ? 1.f : se;
        float val = acc / den;
        size_t o = (size_t)r * 64 + lane;
        if (ACCUM) out[o] += val; else out[o] = val;
    }
}

extern "C" void kernel_launch(void* const* d_in, const int* in_sizes, int n_in,
                              void* d_out, int out_size, void* d_ws, size_t ws_size,
                              hipStream_t stream)
{
    const float* x0  = (const float*)d_in[0];
    const float* x1  = (const float*)d_in[1];
    const float* x2  = (const float*)d_in[2];
    const float* x3  = (const float*)d_in[3];
    const float* x4  = (const float*)d_in[4];
    const int*   adj0 = (const int*)d_in[5];
    const int*   adj1 = (const int*)d_in[6];
    const int*   inct = (const int*)d_in[7];
    const int*   incs = (const int*)d_in[8];
    const float* W0  = (const float*)d_in[9];
    const float* a0  = (const float*)d_in[10];
    const float* W1  = (const float*)d_in[11];
    const float* a1  = (const float*)d_in[12];
    const float* Ws  = (const float*)d_in[13];
    const float* Wt  = (const float*)d_in[14];
    const float* ans = (const float*)d_in[15];

    const int N0  = in_sizes[0] / CDIM;      // 50000
    const int N1  = in_sizes[1] / CDIM;      // 100000
    const int NP  = in_sizes[2];             // passthrough flat size (20000*64)
    const int E0  = in_sizes[5] / 2;         // 800000
    const int E1  = in_sizes[6] / 2;         // 1600000
    const int E01 = in_sizes[7];             // 200000

    float* out0 = (float*)d_out;                    // x_0_level1 [N0*64]
    float* out1 = out0 + (size_t)N0 * CDIM;         // x_1_level1 [N1*64]
    float* outp = out1 + (size_t)N1 * CDIM;         // x_2, x_3, x_4

    // ---- workspace layout ----
    char* w = (char*)d_ws;
    size_t off = 0;
    float* m0  = (float*)(w + off); off += (size_t)N0 * CDIM * 4;
    float* m1  = (float*)(w + off); off += (size_t)N1 * CDIM * 4;
    float* sm  = (float*)(w + off); off += (size_t)N1 * CDIM * 4;
    float* tm  = (float*)(w + off); off += (size_t)N0 * CDIM * 4;
    float* pl0 = (float*)(w + off); off += (size_t)N0 * 4;
    float* pr0 = (float*)(w + off); off += (size_t)N0 * 4;
    float* pl1 = (float*)(w + off); off += (size_t)N1 * 4;
    float* pr1 = (float*)(w + off); off += (size_t)N1 * 4;
    float* pls = (float*)(w + off); off += (size_t)N1 * 4;   // p_s = sm @ a_ns[:C]
    float* prs = (float*)(w + off); off += (size_t)N1 * 4;   // unused half
    float* plt = (float*)(w + off); off += (size_t)N0 * 4;   // unused half
    float* prt = (float*)(w + off); off += (size_t)N0 * 4;   // p_t = tm @ a_ns[C:]
    // cursors (counts -> scan offsets -> post-fill row ends); contiguous for one memset
    int* cur0 = (int*)(w + off); off += (size_t)N0 * 4;
    int* cur1 = (int*)(w + off); off += (size_t)N1 * 4;
    int* curT = (int*)(w + off); off += (size_t)N0 * 4;
    int* curS = (int*)(w + off); off += (size_t)N1 * 4;
    size_t curBytes = ((size_t)N0 + N1 + N0 + N1) * 4;
    int2* csr0 = (int2*)(w + off); off += (size_t)E0  * 8;
    int2* csr1 = (int2*)(w + off); off += (size_t)E1  * 8;
    int2* csrT = (int2*)(w + off); off += (size_t)E01 * 8;
    int2* csrS = (int2*)(w + off); off += (size_t)E01 * 8;
    (void)ws_size; (void)n_in; (void)out_size;

    dim3 blk(256);

    // ---- dense projections ----
    gemm64_kernel<<<1024, blk, 0, stream>>>(x0, W0, a0, m0, pl0, pr0, N0);
    gemm64_kernel<<<1024, blk, 0, stream>>>(x1, W1, a1, m1, pl1, pr1, N1);
    gemm64_kernel<<<1024, blk, 0, stream>>>(x1, Ws, ans, sm, pls, prs, N1);
    gemm64_kernel<<<1024, blk, 0, stream>>>(x0, Wt, ans, tm, plt, prt, N0);

    // ---- CSR build: count -> scan -> fill ----
    hipMemsetAsync(cur0, 0, curBytes, stream);
    count_kernel<<<(E0 + 255) / 256, blk, 0, stream>>>(adj0, cur0, E0);
    count_kernel<<<(E1 + 255) / 256, blk, 0, stream>>>(adj1, cur1, E1);
    count_kernel<<<(E01 + 255) / 256, blk, 0, stream>>>(inct, curT, E01);
    count_kernel<<<(E01 + 255) / 256, blk, 0, stream>>>(incs, curS, E01);

    scan_kernel<<<1, 1024, 0, stream>>>(cur0, N0);
    scan_kernel<<<1, 1024, 0, stream>>>(cur1, N1);
    scan_kernel<<<1, 1024, 0, stream>>>(curT, N0);
    scan_kernel<<<1, 1024, 0, stream>>>(curS, N1);

    // HBS: key=i (adj[0:E]), val=j (adj[E:2E]), e = lrelu(pL[i]+pR[j])
    fill_kernel<<<(E0 + 255) / 256, blk, 0, stream>>>(adj0, adj0 + E0, pl0, pr0, cur0, csr0, E0);
    fill_kernel<<<(E1 + 255) / 256, blk, 0, stream>>>(adj1, adj1 + E1, pl1, pr1, cur1, csr1, E1);
    // HBNS: e = lrelu(p_s[s] + p_t[t]); keyed by t (payload s) and by s (payload t)
    fill_kernel<<<(E01 + 255) / 256, blk, 0, stream>>>(inct, incs, prt, pls, curT, csrT, E01);
    fill_kernel<<<(E01 + 255) / 256, blk, 0, stream>>>(incs, inct, pls, prt, curS, csrS, E01);

    // NOTE on fill_kernel arg order: for HBNS-by-t, pA indexes key (t) -> prt (p_t),
    // pB indexes val (s) -> pls (p_s); e = p_t[t] + p_s[s] == p_s[s] + p_t[t]. Same for by-s.

    // ---- pull gathers (no atomics; one wave owns each output row) ----
    gather_kernel<0><<<(N0 + 3) / 4, blk, 0, stream>>>(cur0, csr0, m0, out0, N0);
    gather_kernel<1><<<(N0 + 3) / 4, blk, 0, stream>>>(curT, csrT, sm, out0, N0);
    gather_kernel<0><<<(N1 + 3) / 4, blk, 0, stream>>>(cur1, csr1, m1, out1, N1);
    gather_kernel<1><<<(N1 + 3) / 4, blk, 0, stream>>>(curS, csrS, tm, out1, N1);

    // ---- passthroughs x_2, x_3, x_4 ----
    hipMemcpyAsync(outp,          x2, (size_t)NP * sizeof(float), hipMemcpyDeviceToDevice, stream);
    hipMemcpyAsync(outp + NP,     x3, (size_t)NP * sizeof(float), hipMemcpyDeviceToDevice, stream);
    hipMemcpyAsync(outp + 2 * NP, x4, (size_t)NP * sizeof(float), hipMemcpyDeviceToDevice, stream);
}

// Round 3
// 772.293 us; speedup vs baseline: 3.6382x; 1.5989x over previous
//
#include <hip/hip_runtime.h>

#define CDIM 64
#define SLOPE 0.2f

// ---------------------------------------------------------------------------
// Y = X @ W   (X: [n,64], W: [64,64]); also pL = Y @ a[0:64], pR = Y @ a[64:128]
// One wave (64 lanes) per row; W and a staged in LDS.
// ---------------------------------------------------------------------------
__global__ void gemm64_kernel(const float* __restrict__ X, const float* __restrict__ W,
                              const float* __restrict__ a, float* __restrict__ Y,
                              float* __restrict__ pL, float* __restrict__ pR, int n)
{
    __shared__ float sW[64 * 64];
    __shared__ float sa[128];
    int tid = threadIdx.x;
    for (int k = tid; k < 64 * 64; k += blockDim.x) sW[k] = W[k];
    if (tid < 128) sa[tid] = a[tid];
    __syncthreads();

    const int lane = tid & 63;
    const int gwave = (int)((blockIdx.x * blockDim.x + tid) >> 6);
    const int nwaves = (int)((gridDim.x * blockDim.x) >> 6);

    for (int r = gwave; r < n; r += nwaves) {
        float x = X[(size_t)r * 64 + lane];
        float acc = 0.f;
#pragma unroll
        for (int k = 0; k < 64; ++k) {
            acc = fmaf(__shfl(x, k, 64), sW[k * 64 + lane], acc);
        }
        Y[(size_t)r * 64 + lane] = acc;
        float l = acc * sa[lane];
        float rr = acc * sa[64 + lane];
#pragma unroll
        for (int off = 32; off; off >>= 1) {
            l += __shfl_xor(l, off, 64);
            rr += __shfl_xor(rr, off, 64);
        }
        if (lane == 0) { pL[r] = l; pR[r] = rr; }
    }
}

// ---------------------------------------------------------------------------
// Histogram of edge targets into cnt[] (int atomics).
// ---------------------------------------------------------------------------
__global__ void count_kernel(const int* __restrict__ keys, int* __restrict__ cnt, int E)
{
    int k = blockIdx.x * blockDim.x + threadIdx.x;
    if (k >= E) return;
    atomicAdd(&cnt[keys[k]], 1);
}

// ---------------------------------------------------------------------------
// 3-kernel global exclusive scan over cnt[0..n) in place, chunk = 2048/block.
// ---------------------------------------------------------------------------
#define SCAN_CHUNK 2048

__global__ void scan_partials(const int* __restrict__ cnt, int* __restrict__ part, int n)
{
    __shared__ int tsum[256];
    int b = blockIdx.x, t = threadIdx.x;
    int base = b * SCAN_CHUNK + t * 8;
    int s = 0;
#pragma unroll
    for (int u = 0; u < 8; ++u) { int idx = base + u; if (idx < n) s += cnt[idx]; }
    tsum[t] = s;
    __syncthreads();
    for (int off = 128; off; off >>= 1) {
        if (t < off) tsum[t] += tsum[t + off];
        __syncthreads();
    }
    if (t == 0) part[b] = tsum[0];
}

__global__ void scan_small(int* __restrict__ part, int n)
{
    __shared__ int sh[256];
    int t = threadIdx.x;
    sh[t] = (t < n) ? part[t] : 0;
    __syncthreads();
    for (int off = 1; off < 256; off <<= 1) {
        int x = (t >= off) ? sh[t - off] : 0;
        __syncthreads();
        sh[t] += x;
        __syncthreads();
    }
    if (t < n) part[t] = (t == 0) ? 0 : sh[t - 1];
}

__global__ void scan_apply(int* __restrict__ cnt, const int* __restrict__ part, int n)
{
    __shared__ int tsum[256];
    int b = blockIdx.x, t = threadIdx.x;
    int base = b * SCAN_CHUNK + t * 8;
    int v[8];
    int s = 0;
#pragma unroll
    for (int u = 0; u < 8; ++u) {
        int idx = base + u;
        v[u] = (idx < n) ? cnt[idx] : 0;
        s += v[u];
    }
    tsum[t] = s;
    __syncthreads();
    for (int off = 1; off < 256; off <<= 1) {
        int x = (t >= off) ? tsum[t - off] : 0;
        __syncthreads();
        tsum[t] += x;
        __syncthreads();
    }
    int pre = part[b] + ((t == 0) ? 0 : tsum[t - 1]);
#pragma unroll
    for (int u = 0; u < 8; ++u) {
        int idx = base + u;
        if (idx < n) cnt[idx] = pre;
        pre += v[u];
    }
}

// ---------------------------------------------------------------------------
// CSR fill: e = leakyrelu(pA[key] + pB[val]); csr[pos] = (val, e)
// pos = atomicAdd(cursor[key]) — cursor holds GLOBAL row-start offsets.
// ---------------------------------------------------------------------------
__global__ void fill_kernel(const int* __restrict__ keys, const int* __restrict__ vals,
                            const float* __restrict__ pA, const float* __restrict__ pB,
                            int* __restrict__ cursor, int2* __restrict__ csr, int E)
{
    int k = blockIdx.x * blockDim.x + threadIdx.x;
    if (k >= E) return;
    int i = keys[k];
    int j = vals[k];
    float v = pA[i] + pB[j];
    v = v > 0.f ? v : SLOPE * v;
    int pos = atomicAdd(&cursor[i], 1);
    csr[pos] = make_int2(j, __float_as_int(v));
}

// ---------------------------------------------------------------------------
// Pull gather: one wave per row r. out[r] (+)= (1/den) * sum_e e * M[j]
// cursor[r] = GLOBAL row end (post-fill); row start = cursor[r-1] (r>0) else base.
// ---------------------------------------------------------------------------
template <int ACCUM>
__global__ void gather_kernel(const int* __restrict__ cursor, int base,
                              const int2* __restrict__ csr,
                              const float* __restrict__ M, float* __restrict__ out, int n)
{
    const int lane = threadIdx.x & 63;
    int wave = (int)((blockIdx.x * blockDim.x + threadIdx.x) >> 6);
    int nw = (int)((gridDim.x * blockDim.x) >> 6);
    for (int r = wave; r < n; r += nw) {
        int p0 = (r == 0) ? base : cursor[r - 1];
        int p1 = cursor[r];
        float acc = 0.f, se = 0.f;
        for (int p = p0; p < p1; p += 64) {
            int q = p + lane;
            int2 je = (q < p1) ? csr[q] : make_int2(0, 0);
            float ef = (q < p1) ? __int_as_float(je.y) : 0.f;
            se += ef;
            int cnt = min(64, p1 - p);
            for (int t = 0; t < cnt; ++t) {
                int jj = __shfl(je.x, t, 64);
                float ee = __shfl(ef, t, 64);
                acc = fmaf(ee, M[(size_t)jj * 64 + lane], acc);
            }
        }
#pragma unroll
        for (int off = 32; off; off >>= 1) se += __shfl_xor(se, off, 64);
        float den = (se == 0.f) ? 1.f : se;
        float val = acc / den;
        size_t o = (size_t)r * 64 + lane;
        if (ACCUM) out[o] += val; else out[o] = val;
    }
}

extern "C" void kernel_launch(void* const* d_in, const int* in_sizes, int n_in,
                              void* d_out, int out_size, void* d_ws, size_t ws_size,
                              hipStream_t stream)
{
    const float* x0  = (const float*)d_in[0];
    const float* x1  = (const float*)d_in[1];
    const float* x2  = (const float*)d_in[2];
    const float* x3  = (const float*)d_in[3];
    const float* x4  = (const float*)d_in[4];
    const int*   adj0 = (const int*)d_in[5];
    const int*   adj1 = (const int*)d_in[6];
    const int*   inct = (const int*)d_in[7];
    const int*   incs = (const int*)d_in[8];
    const float* W0  = (const float*)d_in[9];
    const float* a0  = (const float*)d_in[10];
    const float* W1  = (const float*)d_in[11];
    const float* a1  = (const float*)d_in[12];
    const float* Ws  = (const float*)d_in[13];
    const float* Wt  = (const float*)d_in[14];
    const float* ans = (const float*)d_in[15];

    const int N0  = in_sizes[0] / CDIM;      // 50000
    const int N1  = in_sizes[1] / CDIM;      // 100000
    const int NP  = in_sizes[2];             // passthrough flat size
    const int E0  = in_sizes[5] / 2;         // 800000
    const int E1  = in_sizes[6] / 2;         // 1600000
    const int E01 = in_sizes[7];             // 200000

    float* out0 = (float*)d_out;
    float* out1 = out0 + (size_t)N0 * CDIM;
    float* outp = out1 + (size_t)N1 * CDIM;

    // ---- workspace layout ----
    char* w = (char*)d_ws;
    size_t off = 0;
    float* m0  = (float*)(w + off); off += (size_t)N0 * CDIM * 4;
    float* m1  = (float*)(w + off); off += (size_t)N1 * CDIM * 4;
    float* sm  = (float*)(w + off); off += (size_t)N1 * CDIM * 4;
    float* tm  = (float*)(w + off); off += (size_t)N0 * CDIM * 4;
    float* pl0 = (float*)(w + off); off += (size_t)N0 * 4;
    float* pr0 = (float*)(w + off); off += (size_t)N0 * 4;
    float* pl1 = (float*)(w + off); off += (size_t)N1 * 4;
    float* pr1 = (float*)(w + off); off += (size_t)N1 * 4;
    float* pls = (float*)(w + off); off += (size_t)N1 * 4;   // p_s = sm @ a_ns[:C]
    float* prs = (float*)(w + off); off += (size_t)N1 * 4;   // unused half
    float* plt = (float*)(w + off); off += (size_t)N0 * 4;   // unused half
    float* prt = (float*)(w + off); off += (size_t)N0 * 4;   // p_t = tm @ a_ns[C:]
    // cursors: contiguous concatenation -> one global scan gives absolute csr offsets
    int* curAll = (int*)(w + off);
    int* cur0 = curAll;            // N0
    int* cur1 = cur0 + N0;         // N1
    int* curT = cur1 + N1;         // N0
    int* curS = curT + N0;         // N1
    const int Ntot = N0 + N1 + N0 + N1;
    off += (size_t)Ntot * 4;
    int* part = (int*)(w + off); off += 1024 * 4;   // scan partials
    int2* csrAll = (int2*)(w + off); off += ((size_t)E0 + E1 + 2 * (size_t)E01) * 8;
    (void)ws_size; (void)n_in; (void)out_size;

    // global bases of each array's region within csrAll
    const int base0 = 0;
    const int base1 = E0;
    const int baseT = E0 + E1;
    const int baseS = E0 + E1 + E01;

    dim3 blk(256);

    // ---- dense projections ----
    gemm64_kernel<<<1024, blk, 0, stream>>>(x0, W0, a0, m0, pl0, pr0, N0);
    gemm64_kernel<<<1024, blk, 0, stream>>>(x1, W1, a1, m1, pl1, pr1, N1);
    gemm64_kernel<<<1024, blk, 0, stream>>>(x1, Ws, ans, sm, pls, prs, N1);
    gemm64_kernel<<<1024, blk, 0, stream>>>(x0, Wt, ans, tm, plt, prt, N0);

    // ---- CSR build: count -> global scan -> fill ----
    hipMemsetAsync(curAll, 0, (size_t)Ntot * 4, stream);
    count_kernel<<<(E0 + 255) / 256, blk, 0, stream>>>(adj0, cur0, E0);
    count_kernel<<<(E1 + 255) / 256, blk, 0, stream>>>(adj1, cur1, E1);
    count_kernel<<<(E01 + 255) / 256, blk, 0, stream>>>(inct, curT, E01);
    count_kernel<<<(E01 + 255) / 256, blk, 0, stream>>>(incs, curS, E01);

    int nCh = (Ntot + SCAN_CHUNK - 1) / SCAN_CHUNK;   // ~147 (<=256)
    scan_partials<<<nCh, blk, 0, stream>>>(curAll, part, Ntot);
    scan_small<<<1, blk, 0, stream>>>(part, nCh);
    scan_apply<<<nCh, blk, 0, stream>>>(curAll, part, Ntot);

    // HBS: key=i (adj[0:E]), val=j (adj[E:2E]), e = lrelu(pL[i]+pR[j])
    fill_kernel<<<(E0 + 255) / 256, blk, 0, stream>>>(adj0, adj0 + E0, pl0, pr0, cur0, csrAll, E0);
    fill_kernel<<<(E1 + 255) / 256, blk, 0, stream>>>(adj1, adj1 + E1, pl1, pr1, cur1, csrAll, E1);
    // HBNS: e = lrelu(p_s[s] + p_t[t]); keyed by t (payload s) and by s (payload t)
    fill_kernel<<<(E01 + 255) / 256, blk, 0, stream>>>(inct, incs, prt, pls, curT, csrAll, E01);
    fill_kernel<<<(E01 + 255) / 256, blk, 0, stream>>>(incs, inct, pls, prt, curS, csrAll, E01);

    // ---- pull gathers (no atomics; one wave owns each output row) ----
    gather_kernel<0><<<(N0 + 3) / 4, blk, 0, stream>>>(cur0, base0, csrAll, m0, out0, N0);
    gather_kernel<1><<<(N0 + 3) / 4, blk, 0, stream>>>(curT, baseT, csrAll, sm, out0, N0);
    gather_kernel<0><<<(N1 + 3) / 4, blk, 0, stream>>>(cur1, base1, csrAll, m1, out1, N1);
    gather_kernel<1><<<(N1 + 3) / 4, blk, 0, stream>>>(curS, baseS, csrAll, tm, out1, N1);

    // ---- passthroughs x_2, x_3, x_4 ----
    hipMemcpyAsync(outp,          x2, (size_t)NP * sizeof(float), hipMemcpyDeviceToDevice, stream);
    hipMemcpyAsync(outp + NP,     x3, (size_t)NP * sizeof(float), hipMemcpyDeviceToDevice, stream);
    hipMemcpyAsync(outp + 2 * NP, x4, (size_t)NP * sizeof(float), hipMemcpyDeviceToDevice, stream);
}

// Round 4
// 675.694 us; speedup vs baseline: 4.1583x; 1.1430x over previous
//
#include <hip/hip_runtime.h>

#define CDIM 64
#define SLOPE 0.2f

// ---------------------------------------------------------------------------
// Dual GEMM: Ya = X@Wa, Yb = X@Wb (X read once, shuffle broadcast shared).
// Also pLa = Ya@aa[:64], pRa = Ya@aa[64:], same for b.
// ---------------------------------------------------------------------------
__global__ void gemm64x2_kernel(const float* __restrict__ X,
                                const float* __restrict__ Wa, const float* __restrict__ aa,
                                float* __restrict__ Ya, float* __restrict__ pLa, float* __restrict__ pRa,
                                const float* __restrict__ Wb, const float* __restrict__ ab,
                                float* __restrict__ Yb, float* __restrict__ pLb, float* __restrict__ pRb,
                                int n)
{
    __shared__ float sWa[64 * 64];
    __shared__ float sWb[64 * 64];
    __shared__ float saa[128], sab[128];
    int tid = threadIdx.x;
    for (int k = tid; k < 64 * 64; k += blockDim.x) { sWa[k] = Wa[k]; sWb[k] = Wb[k]; }
    if (tid < 128) { saa[tid] = aa[tid]; sab[tid] = ab[tid]; }
    __syncthreads();

    const int lane = tid & 63;
    int wave = (int)((blockIdx.x * blockDim.x + tid) >> 6);
    int nw = (int)((gridDim.x * blockDim.x) >> 6);

    for (int r = wave; r < n; r += nw) {
        float x = X[(size_t)r * 64 + lane];
        float acca = 0.f, accb = 0.f;
#pragma unroll
        for (int k = 0; k < 64; ++k) {
            float xs = __shfl(x, k, 64);
            acca = fmaf(xs, sWa[k * 64 + lane], acca);
            accb = fmaf(xs, sWb[k * 64 + lane], accb);
        }
        Ya[(size_t)r * 64 + lane] = acca;
        Yb[(size_t)r * 64 + lane] = accb;
        float la = acca * saa[lane], ra = acca * saa[64 + lane];
        float lb = accb * sab[lane], rb = accb * sab[64 + lane];
#pragma unroll
        for (int off = 32; off; off >>= 1) {
            la += __shfl_xor(la, off, 64); ra += __shfl_xor(ra, off, 64);
            lb += __shfl_xor(lb, off, 64); rb += __shfl_xor(rb, off, 64);
        }
        if (lane == 0) { pLa[r] = la; pRa[r] = ra; pLb[r] = lb; pRb[r] = rb; }
    }
}

// ---------------------------------------------------------------------------
// Histogram of edge targets into cnt[] (int atomics).
// ---------------------------------------------------------------------------
__global__ void count_kernel(const int* __restrict__ keys, int* __restrict__ cnt, int E)
{
    int k = blockIdx.x * blockDim.x + threadIdx.x;
    if (k >= E) return;
    atomicAdd(&cnt[keys[k]], 1);
}

// ---------------------------------------------------------------------------
// 3-kernel global exclusive scan over cnt[0..n) in place, chunk = 2048/block.
// ---------------------------------------------------------------------------
#define SCAN_CHUNK 2048

__global__ void scan_partials(const int* __restrict__ cnt, int* __restrict__ part, int n)
{
    __shared__ int tsum[256];
    int b = blockIdx.x, t = threadIdx.x;
    int base = b * SCAN_CHUNK + t * 8;
    int s = 0;
#pragma unroll
    for (int u = 0; u < 8; ++u) { int idx = base + u; if (idx < n) s += cnt[idx]; }
    tsum[t] = s;
    __syncthreads();
    for (int off = 128; off; off >>= 1) {
        if (t < off) tsum[t] += tsum[t + off];
        __syncthreads();
    }
    if (t == 0) part[b] = tsum[0];
}

__global__ void scan_small(int* __restrict__ part, int n)
{
    __shared__ int sh[256];
    int t = threadIdx.x;
    sh[t] = (t < n) ? part[t] : 0;
    __syncthreads();
    for (int off = 1; off < 256; off <<= 1) {
        int x = (t >= off) ? sh[t - off] : 0;
        __syncthreads();
        sh[t] += x;
        __syncthreads();
    }
    if (t < n) part[t] = (t == 0) ? 0 : sh[t - 1];
}

__global__ void scan_apply(int* __restrict__ cnt, const int* __restrict__ part, int n)
{
    __shared__ int tsum[256];
    int b = blockIdx.x, t = threadIdx.x;
    int base = b * SCAN_CHUNK + t * 8;
    int v[8];
    int s = 0;
#pragma unroll
    for (int u = 0; u < 8; ++u) {
        int idx = base + u;
        v[u] = (idx < n) ? cnt[idx] : 0;
        s += v[u];
    }
    tsum[t] = s;
    __syncthreads();
    for (int off = 1; off < 256; off <<= 1) {
        int x = (t >= off) ? tsum[t - off] : 0;
        __syncthreads();
        tsum[t] += x;
        __syncthreads();
    }
    int pre = part[b] + ((t == 0) ? 0 : tsum[t - 1]);
#pragma unroll
    for (int u = 0; u < 8; ++u) {
        int idx = base + u;
        if (idx < n) cnt[idx] = pre;
        pre += v[u];
    }
}

// ---------------------------------------------------------------------------
// CSR fill: e = leakyrelu(pA[key] + pB[val]); csr[pos] = (val, e)
// pos = atomicAdd(cursor[key]) — cursor holds GLOBAL row-start offsets.
// ---------------------------------------------------------------------------
__global__ void fill_kernel(const int* __restrict__ keys, const int* __restrict__ vals,
                            const float* __restrict__ pA, const float* __restrict__ pB,
                            int* __restrict__ cursor, int2* __restrict__ csr, int E)
{
    int k = blockIdx.x * blockDim.x + threadIdx.x;
    if (k >= E) return;
    int i = keys[k];
    int j = vals[k];
    float v = pA[i] + pB[j];
    v = v > 0.f ? v : SLOPE * v;
    int pos = atomicAdd(&cursor[i], 1);
    csr[pos] = make_int2(j, __float_as_int(v));
}

// ---------------------------------------------------------------------------
// Fused dual pull-gather: one wave per output row r.
//   out[r] = gatherA(r)/denA + gatherB(r)/denB        (single write, no RMW)
// Layout: 4 edge-groups of 16 lanes; group g handles edge p+g; lane owns
// channels c4..c4+3 via float4. Cross-group reduce with 2x shfl_xor at end.
// ---------------------------------------------------------------------------
__global__ void gather2_kernel(const int* __restrict__ curA, int baseA, const float* __restrict__ MA,
                               const int* __restrict__ curB, int baseB, const float* __restrict__ MB,
                               const int2* __restrict__ csr, float* __restrict__ out, int n)
{
    const int lane = threadIdx.x & 63;
    const int g = lane >> 4;            // edge-group 0..3
    const int c4 = (lane & 15) << 2;    // channel base
    int wave = (int)((blockIdx.x * blockDim.x + threadIdx.x) >> 6);
    int nw = (int)((gridDim.x * blockDim.x) >> 6);

    for (int r = wave; r < n; r += nw) {
        float4 accA = make_float4(0.f, 0.f, 0.f, 0.f);
        float4 accB = make_float4(0.f, 0.f, 0.f, 0.f);
        float seA = 0.f, seB = 0.f;

        {
            int p0 = (r == 0) ? baseA : curA[r - 1];
            int p1 = curA[r];
#pragma unroll 2
            for (int p = p0; p < p1; p += 4) {
                int idx = p + g;
                int2 je = make_int2(0, 0);
                if (idx < p1) je = csr[idx];
                float e = __int_as_float(je.y);
                seA += e;
                const float4 row = *reinterpret_cast<const float4*>(MA + (size_t)je.x * 64 + c4);
                accA.x = fmaf(e, row.x, accA.x);
                accA.y = fmaf(e, row.y, accA.y);
                accA.z = fmaf(e, row.z, accA.z);
                accA.w = fmaf(e, row.w, accA.w);
            }
        }
        {
            int p0 = (r == 0) ? baseB : curB[r - 1];
            int p1 = curB[r];
#pragma unroll 2
            for (int p = p0; p < p1; p += 4) {
                int idx = p + g;
                int2 je = make_int2(0, 0);
                if (idx < p1) je = csr[idx];
                float e = __int_as_float(je.y);
                seB += e;
                const float4 row = *reinterpret_cast<const float4*>(MB + (size_t)je.x * 64 + c4);
                accB.x = fmaf(e, row.x, accB.x);
                accB.y = fmaf(e, row.y, accB.y);
                accB.z = fmaf(e, row.z, accB.z);
                accB.w = fmaf(e, row.w, accB.w);
            }
        }

        // reduce row-sums across the 4 groups (lanes within a group are identical)
        seA += __shfl_xor(seA, 16, 64); seA += __shfl_xor(seA, 32, 64);
        seB += __shfl_xor(seB, 16, 64); seB += __shfl_xor(seB, 32, 64);
        float rA = 1.f / ((seA == 0.f) ? 1.f : seA);
        float rB = 1.f / ((seB == 0.f) ? 1.f : seB);

        float4 part;
        part.x = accA.x * rA + accB.x * rB;
        part.y = accA.y * rA + accB.y * rB;
        part.z = accA.z * rA + accB.z * rB;
        part.w = accA.w * rA + accB.w * rB;
        part.x += __shfl_xor(part.x, 16, 64); part.x += __shfl_xor(part.x, 32, 64);
        part.y += __shfl_xor(part.y, 16, 64); part.y += __shfl_xor(part.y, 32, 64);
        part.z += __shfl_xor(part.z, 16, 64); part.z += __shfl_xor(part.z, 32, 64);
        part.w += __shfl_xor(part.w, 16, 64); part.w += __shfl_xor(part.w, 32, 64);

        if (g == 0) *reinterpret_cast<float4*>(out + (size_t)r * 64 + c4) = part;
    }
}

extern "C" void kernel_launch(void* const* d_in, const int* in_sizes, int n_in,
                              void* d_out, int out_size, void* d_ws, size_t ws_size,
                              hipStream_t stream)
{
    const float* x0  = (const float*)d_in[0];
    const float* x1  = (const float*)d_in[1];
    const float* x2  = (const float*)d_in[2];
    const float* x3  = (const float*)d_in[3];
    const float* x4  = (const float*)d_in[4];
    const int*   adj0 = (const int*)d_in[5];
    const int*   adj1 = (const int*)d_in[6];
    const int*   inct = (const int*)d_in[7];
    const int*   incs = (const int*)d_in[8];
    const float* W0  = (const float*)d_in[9];
    const float* a0  = (const float*)d_in[10];
    const float* W1  = (const float*)d_in[11];
    const float* a1  = (const float*)d_in[12];
    const float* Ws  = (const float*)d_in[13];
    const float* Wt  = (const float*)d_in[14];
    const float* ans = (const float*)d_in[15];

    const int N0  = in_sizes[0] / CDIM;      // 50000
    const int N1  = in_sizes[1] / CDIM;      // 100000
    const int NP  = in_sizes[2];             // passthrough flat size
    const int E0  = in_sizes[5] / 2;         // 800000
    const int E1  = in_sizes[6] / 2;         // 1600000
    const int E01 = in_sizes[7];             // 200000

    float* out0 = (float*)d_out;
    float* out1 = out0 + (size_t)N0 * CDIM;
    float* outp = out1 + (size_t)N1 * CDIM;

    // ---- workspace layout ----
    char* w = (char*)d_ws;
    size_t off = 0;
    float* m0  = (float*)(w + off); off += (size_t)N0 * CDIM * 4;
    float* m1  = (float*)(w + off); off += (size_t)N1 * CDIM * 4;
    float* sm  = (float*)(w + off); off += (size_t)N1 * CDIM * 4;
    float* tm  = (float*)(w + off); off += (size_t)N0 * CDIM * 4;
    float* pl0 = (float*)(w + off); off += (size_t)N0 * 4;
    float* pr0 = (float*)(w + off); off += (size_t)N0 * 4;
    float* pl1 = (float*)(w + off); off += (size_t)N1 * 4;
    float* pr1 = (float*)(w + off); off += (size_t)N1 * 4;
    float* pls = (float*)(w + off); off += (size_t)N1 * 4;   // p_s = sm @ a_ns[:C]
    float* prs = (float*)(w + off); off += (size_t)N1 * 4;   // unused half
    float* plt = (float*)(w + off); off += (size_t)N0 * 4;   // unused half
    float* prt = (float*)(w + off); off += (size_t)N0 * 4;   // p_t = tm @ a_ns[C:]
    // cursors: contiguous concatenation -> one global scan gives absolute csr offsets
    int* curAll = (int*)(w + off);
    int* cur0 = curAll;            // N0
    int* cur1 = cur0 + N0;         // N1
    int* curT = cur1 + N1;         // N0
    int* curS = curT + N0;         // N1
    const int Ntot = N0 + N1 + N0 + N1;
    off += (size_t)Ntot * 4;
    int* part = (int*)(w + off); off += 1024 * 4;   // scan partials
    int2* csrAll = (int2*)(w + off); off += ((size_t)E0 + E1 + 2 * (size_t)E01) * 8;
    (void)ws_size; (void)n_in; (void)out_size;

    // global bases of each array's region within csrAll
    const int base0 = 0;
    const int base1 = E0;
    const int baseT = E0 + E1;
    const int baseS = E0 + E1 + E01;

    dim3 blk(256);

    // ---- CSR build: count -> global scan ----
    hipMemsetAsync(curAll, 0, (size_t)Ntot * 4, stream);
    count_kernel<<<(E0 + 255) / 256, blk, 0, stream>>>(adj0, cur0, E0);
    count_kernel<<<(E1 + 255) / 256, blk, 0, stream>>>(adj1, cur1, E1);
    count_kernel<<<(E01 + 255) / 256, blk, 0, stream>>>(inct, curT, E01);
    count_kernel<<<(E01 + 255) / 256, blk, 0, stream>>>(incs, curS, E01);

    int nCh = (Ntot + SCAN_CHUNK - 1) / SCAN_CHUNK;   // ~147 (<=256)
    scan_partials<<<nCh, blk, 0, stream>>>(curAll, part, Ntot);
    scan_small<<<1, blk, 0, stream>>>(part, nCh);
    scan_apply<<<nCh, blk, 0, stream>>>(curAll, part, Ntot);

    // ---- fused dense projections ----
    gemm64x2_kernel<<<1024, blk, 0, stream>>>(x0, W0, a0, m0, pl0, pr0,
                                              Wt, ans, tm, plt, prt, N0);
    gemm64x2_kernel<<<1024, blk, 0, stream>>>(x1, W1, a1, m1, pl1, pr1,
                                              Ws, ans, sm, pls, prs, N1);

    // ---- fills ----
    // HBS: key=i (adj[0:E]), val=j (adj[E:2E]), e = lrelu(pL[i]+pR[j])
    fill_kernel<<<(E0 + 255) / 256, blk, 0, stream>>>(adj0, adj0 + E0, pl0, pr0, cur0, csrAll, E0);
    fill_kernel<<<(E1 + 255) / 256, blk, 0, stream>>>(adj1, adj1 + E1, pl1, pr1, cur1, csrAll, E1);
    // HBNS: e = lrelu(p_s[s] + p_t[t]); keyed by t (payload s) and by s (payload t)
    fill_kernel<<<(E01 + 255) / 256, blk, 0, stream>>>(inct, incs, prt, pls, curT, csrAll, E01);
    fill_kernel<<<(E01 + 255) / 256, blk, 0, stream>>>(incs, inct, pls, prt, curS, csrAll, E01);

    // ---- fused pull gathers: out = A/denA + B/denB, single write ----
    gather2_kernel<<<2048, blk, 0, stream>>>(cur0, base0, m0, curT, baseT, sm, csrAll, out0, N0);
    gather2_kernel<<<2048, blk, 0, stream>>>(cur1, base1, m1, curS, baseS, tm, csrAll, out1, N1);

    // ---- passthroughs x_2, x_3, x_4 ----
    hipMemcpyAsync(outp,          x2, (size_t)NP * sizeof(float), hipMemcpyDeviceToDevice, stream);
    hipMemcpyAsync(outp + NP,     x3, (size_t)NP * sizeof(float), hipMemcpyDeviceToDevice, stream);
    hipMemcpyAsync(outp + 2 * NP, x4, (size_t)NP * sizeof(float), hipMemcpyDeviceToDevice, stream);
}

// Round 5
// 493.172 us; speedup vs baseline: 5.6973x; 1.3701x over previous
//
#include <hip/hip_runtime.h>

#define CDIM 64
#define SLOPE 0.2f

// ---------------------------------------------------------------------------
// Tiled dual GEMM, shuffle-free: Ya = X@Wa, Yb = X@Wb.
// Block = 256 threads (4 waves). Per 64-row tile: X staged row-major in LDS
// (stride 68, uniform-broadcast float4 reads), W staged transposed
// (stride 66, float2 reads -> 2-way bank alias = free). Wave q owns rows
// q*16..q*16+15, lane owns channel c=lane. Inner loop is pure FMA.
// ---------------------------------------------------------------------------
__global__ void gemm64x2_tiled(const float* __restrict__ X,
                               const float* __restrict__ Wa, float* __restrict__ Ya,
                               const float* __restrict__ Wb, float* __restrict__ Yb,
                               int n)
{
    __shared__ float sX[64 * 68];      // [row][k], stride 68 (272 B, 16B-aligned)
    __shared__ float sWaT[64 * 66];    // [c][k],  stride 66 (264 B, 8B-aligned)
    __shared__ float sWbT[64 * 66];
    const int tid = threadIdx.x;
    const int lane = tid & 63;
    const int q = tid >> 6;

    // stage transposed weights once per block
    for (int idx = tid; idx < 4096; idx += 256) {
        int k = idx >> 6, c = idx & 63;
        sWaT[c * 66 + k] = Wa[idx];
        sWbT[c * 66 + k] = Wb[idx];
    }

    const int ntiles = (n + 63) >> 6;
    for (int tile = blockIdx.x; tile < ntiles; tile += gridDim.x) {
        const int rowbase = tile << 6;
        __syncthreads();   // previous tile's readers done (also covers W staging)
#pragma unroll
        for (int i = 0; i < 4; ++i) {
            int f = tid + i * 256;         // float4 index 0..1023
            int r = f >> 4, k4 = f & 15;
            int row = rowbase + r;
            float4 v = make_float4(0.f, 0.f, 0.f, 0.f);
            if (row < n) v = *reinterpret_cast<const float4*>(X + (size_t)row * 64 + k4 * 4);
            *reinterpret_cast<float4*>(&sX[r * 68 + k4 * 4]) = v;
        }
        __syncthreads();

        const int r0 = q * 16;
        float accA[16], accB[16];
#pragma unroll
        for (int r = 0; r < 16; ++r) { accA[r] = 0.f; accB[r] = 0.f; }

        for (int k4 = 0; k4 < 16; ++k4) {
            const float2 wa0 = *reinterpret_cast<const float2*>(&sWaT[lane * 66 + k4 * 4]);
            const float2 wa1 = *reinterpret_cast<const float2*>(&sWaT[lane * 66 + k4 * 4 + 2]);
            const float2 wb0 = *reinterpret_cast<const float2*>(&sWbT[lane * 66 + k4 * 4]);
            const float2 wb1 = *reinterpret_cast<const float2*>(&sWbT[lane * 66 + k4 * 4 + 2]);
#pragma unroll
            for (int r = 0; r < 16; ++r) {
                const float4 xv = *reinterpret_cast<const float4*>(&sX[(r0 + r) * 68 + k4 * 4]);
                accA[r] = fmaf(xv.x, wa0.x, accA[r]);
                accA[r] = fmaf(xv.y, wa0.y, accA[r]);
                accA[r] = fmaf(xv.z, wa1.x, accA[r]);
                accA[r] = fmaf(xv.w, wa1.y, accA[r]);
                accB[r] = fmaf(xv.x, wb0.x, accB[r]);
                accB[r] = fmaf(xv.y, wb0.y, accB[r]);
                accB[r] = fmaf(xv.z, wb1.x, accB[r]);
                accB[r] = fmaf(xv.w, wb1.y, accB[r]);
            }
        }
#pragma unroll
        for (int r = 0; r < 16; ++r) {
            int row = rowbase + r0 + r;
            if (row < n) {
                Ya[(size_t)row * 64 + lane] = accA[r];
                Yb[(size_t)row * 64 + lane] = accB[r];
            }
        }
    }
}

// ---------------------------------------------------------------------------
// p-pass: one thread per row, fully in-register dual dot product (no shuffles).
// Sections: [0,N0)->m0/a0, [N0,N0+N1)->m1/a1, [..+N1)->sm/ans, [..+N0)->tm/ans.
// ---------------------------------------------------------------------------
__global__ void ppass_kernel(const float* __restrict__ m0, const float* __restrict__ m1,
                             const float* __restrict__ sm, const float* __restrict__ tm,
                             const float* __restrict__ a0, const float* __restrict__ a1,
                             const float* __restrict__ ans,
                             float* __restrict__ pl0, float* __restrict__ pr0,
                             float* __restrict__ pl1, float* __restrict__ pr1,
                             float* __restrict__ pls, float* __restrict__ prs,
                             float* __restrict__ plt, float* __restrict__ prt,
                             int N0, int N1)
{
    int g = blockIdx.x * blockDim.x + threadIdx.x;
    if (g >= 2 * (N0 + N1)) return;
    const float* M; const float* a; float* pL; float* pR; int r;
    if (g < N0)                { M = m0; a = a0;  pL = pl0; pR = pr0; r = g; }
    else if (g < N0 + N1)      { M = m1; a = a1;  pL = pl1; pR = pr1; r = g - N0; }
    else if (g < N0 + 2 * N1)  { M = sm; a = ans; pL = pls; pR = prs; r = g - N0 - N1; }
    else                       { M = tm; a = ans; pL = plt; pR = prt; r = g - N0 - 2 * N1; }

    const float4* row = reinterpret_cast<const float4*>(M + (size_t)r * 64);
    float sl = 0.f, sr = 0.f;
#pragma unroll
    for (int k4 = 0; k4 < 16; ++k4) {
        float4 xv = row[k4];
        float4 al = *reinterpret_cast<const float4*>(a + k4 * 4);
        float4 ar = *reinterpret_cast<const float4*>(a + 64 + k4 * 4);
        sl = fmaf(xv.x, al.x, sl); sl = fmaf(xv.y, al.y, sl);
        sl = fmaf(xv.z, al.z, sl); sl = fmaf(xv.w, al.w, sl);
        sr = fmaf(xv.x, ar.x, sr); sr = fmaf(xv.y, ar.y, sr);
        sr = fmaf(xv.z, ar.z, sr); sr = fmaf(xv.w, ar.w, sr);
    }
    pL[r] = sl;
    pR[r] = sr;
}

// ---------------------------------------------------------------------------
// Histogram of edge targets into cnt[] (int atomics).
// ---------------------------------------------------------------------------
__global__ void count_kernel(const int* __restrict__ keys, int* __restrict__ cnt, int E)
{
    int k = blockIdx.x * blockDim.x + threadIdx.x;
    if (k >= E) return;
    atomicAdd(&cnt[keys[k]], 1);
}

// ---------------------------------------------------------------------------
// 3-kernel global exclusive scan over cnt[0..n) in place, chunk = 2048/block.
// ---------------------------------------------------------------------------
#define SCAN_CHUNK 2048

__global__ void scan_partials(const int* __restrict__ cnt, int* __restrict__ part, int n)
{
    __shared__ int tsum[256];
    int b = blockIdx.x, t = threadIdx.x;
    int base = b * SCAN_CHUNK + t * 8;
    int s = 0;
#pragma unroll
    for (int u = 0; u < 8; ++u) { int idx = base + u; if (idx < n) s += cnt[idx]; }
    tsum[t] = s;
    __syncthreads();
    for (int off = 128; off; off >>= 1) {
        if (t < off) tsum[t] += tsum[t + off];
        __syncthreads();
    }
    if (t == 0) part[b] = tsum[0];
}

__global__ void scan_small(int* __restrict__ part, int n)
{
    __shared__ int sh[256];
    int t = threadIdx.x;
    sh[t] = (t < n) ? part[t] : 0;
    __syncthreads();
    for (int off = 1; off < 256; off <<= 1) {
        int x = (t >= off) ? sh[t - off] : 0;
        __syncthreads();
        sh[t] += x;
        __syncthreads();
    }
    if (t < n) part[t] = (t == 0) ? 0 : sh[t - 1];
}

__global__ void scan_apply(int* __restrict__ cnt, const int* __restrict__ part, int n)
{
    __shared__ int tsum[256];
    int b = blockIdx.x, t = threadIdx.x;
    int base = b * SCAN_CHUNK + t * 8;
    int v[8];
    int s = 0;
#pragma unroll
    for (int u = 0; u < 8; ++u) {
        int idx = base + u;
        v[u] = (idx < n) ? cnt[idx] : 0;
        s += v[u];
    }
    tsum[t] = s;
    __syncthreads();
    for (int off = 1; off < 256; off <<= 1) {
        int x = (t >= off) ? tsum[t - off] : 0;
        __syncthreads();
        tsum[t] += x;
        __syncthreads();
    }
    int pre = part[b] + ((t == 0) ? 0 : tsum[t - 1]);
#pragma unroll
    for (int u = 0; u < 8; ++u) {
        int idx = base + u;
        if (idx < n) cnt[idx] = pre;
        pre += v[u];
    }
}

// ---------------------------------------------------------------------------
// CSR fill: e = leakyrelu(pA[key] + pB[val]); csr[pos] = (val, e)
// pos = atomicAdd(cursor[key]) — cursor holds GLOBAL row-start offsets.
// ---------------------------------------------------------------------------
__global__ void fill_kernel(const int* __restrict__ keys, const int* __restrict__ vals,
                            const float* __restrict__ pA, const float* __restrict__ pB,
                            int* __restrict__ cursor, int2* __restrict__ csr, int E)
{
    int k = blockIdx.x * blockDim.x + threadIdx.x;
    if (k >= E) return;
    int i = keys[k];
    int j = vals[k];
    float v = pA[i] + pB[j];
    v = v > 0.f ? v : SLOPE * v;
    int pos = atomicAdd(&cursor[i], 1);
    csr[pos] = make_int2(j, __float_as_int(v));
}

// ---------------------------------------------------------------------------
// Fused dual pull-gather: one wave per output row r.
//   out[r] = gatherA(r)/denA + gatherB(r)/denB        (single write, no RMW)
// 4 edge-groups of 16 lanes; group g handles edge p+g; lane owns 4 channels.
// ---------------------------------------------------------------------------
__global__ void gather2_kernel(const int* __restrict__ curA, int baseA, const float* __restrict__ MA,
                               const int* __restrict__ curB, int baseB, const float* __restrict__ MB,
                               const int2* __restrict__ csr, float* __restrict__ out, int n)
{
    const int lane = threadIdx.x & 63;
    const int g = lane >> 4;            // edge-group 0..3
    const int c4 = (lane & 15) << 2;    // channel base
    int wave = (int)((blockIdx.x * blockDim.x + threadIdx.x) >> 6);
    int nw = (int)((gridDim.x * blockDim.x) >> 6);

    for (int r = wave; r < n; r += nw) {
        float4 accA = make_float4(0.f, 0.f, 0.f, 0.f);
        float4 accB = make_float4(0.f, 0.f, 0.f, 0.f);
        float seA = 0.f, seB = 0.f;

        {
            int p0 = (r == 0) ? baseA : curA[r - 1];
            int p1 = curA[r];
#pragma unroll 2
            for (int p = p0; p < p1; p += 4) {
                int idx = p + g;
                int2 je = make_int2(0, 0);
                if (idx < p1) je = csr[idx];
                float e = __int_as_float(je.y);
                seA += e;
                const float4 row = *reinterpret_cast<const float4*>(MA + (size_t)je.x * 64 + c4);
                accA.x = fmaf(e, row.x, accA.x);
                accA.y = fmaf(e, row.y, accA.y);
                accA.z = fmaf(e, row.z, accA.z);
                accA.w = fmaf(e, row.w, accA.w);
            }
        }
        {
            int p0 = (r == 0) ? baseB : curB[r - 1];
            int p1 = curB[r];
#pragma unroll 2
            for (int p = p0; p < p1; p += 4) {
                int idx = p + g;
                int2 je = make_int2(0, 0);
                if (idx < p1) je = csr[idx];
                float e = __int_as_float(je.y);
                seB += e;
                const float4 row = *reinterpret_cast<const float4*>(MB + (size_t)je.x * 64 + c4);
                accB.x = fmaf(e, row.x, accB.x);
                accB.y = fmaf(e, row.y, accB.y);
                accB.z = fmaf(e, row.z, accB.z);
                accB.w = fmaf(e, row.w, accB.w);
            }
        }

        seA += __shfl_xor(seA, 16, 64); seA += __shfl_xor(seA, 32, 64);
        seB += __shfl_xor(seB, 16, 64); seB += __shfl_xor(seB, 32, 64);
        float rA = 1.f / ((seA == 0.f) ? 1.f : seA);
        float rB = 1.f / ((seB == 0.f) ? 1.f : seB);

        float4 part;
        part.x = accA.x * rA + accB.x * rB;
        part.y = accA.y * rA + accB.y * rB;
        part.z = accA.z * rA + accB.z * rB;
        part.w = accA.w * rA + accB.w * rB;
        part.x += __shfl_xor(part.x, 16, 64); part.x += __shfl_xor(part.x, 32, 64);
        part.y += __shfl_xor(part.y, 16, 64); part.y += __shfl_xor(part.y, 32, 64);
        part.z += __shfl_xor(part.z, 16, 64); part.z += __shfl_xor(part.z, 32, 64);
        part.w += __shfl_xor(part.w, 16, 64); part.w += __shfl_xor(part.w, 32, 64);

        if (g == 0) *reinterpret_cast<float4*>(out + (size_t)r * 64 + c4) = part;
    }
}

extern "C" void kernel_launch(void* const* d_in, const int* in_sizes, int n_in,
                              void* d_out, int out_size, void* d_ws, size_t ws_size,
                              hipStream_t stream)
{
    const float* x0  = (const float*)d_in[0];
    const float* x1  = (const float*)d_in[1];
    const float* x2  = (const float*)d_in[2];
    const float* x3  = (const float*)d_in[3];
    const float* x4  = (const float*)d_in[4];
    const int*   adj0 = (const int*)d_in[5];
    const int*   adj1 = (const int*)d_in[6];
    const int*   inct = (const int*)d_in[7];
    const int*   incs = (const int*)d_in[8];
    const float* W0  = (const float*)d_in[9];
    const float* a0  = (const float*)d_in[10];
    const float* W1  = (const float*)d_in[11];
    const float* a1  = (const float*)d_in[12];
    const float* Ws  = (const float*)d_in[13];
    const float* Wt  = (const float*)d_in[14];
    const float* ans = (const float*)d_in[15];

    const int N0  = in_sizes[0] / CDIM;      // 50000
    const int N1  = in_sizes[1] / CDIM;      // 100000
    const int NP  = in_sizes[2];             // passthrough flat size
    const int E0  = in_sizes[5] / 2;         // 800000
    const int E1  = in_sizes[6] / 2;         // 1600000
    const int E01 = in_sizes[7];             // 200000

    float* out0 = (float*)d_out;
    float* out1 = out0 + (size_t)N0 * CDIM;
    float* outp = out1 + (size_t)N1 * CDIM;

    // ---- workspace layout ----
    char* w = (char*)d_ws;
    size_t off = 0;
    float* m0  = (float*)(w + off); off += (size_t)N0 * CDIM * 4;
    float* m1  = (float*)(w + off); off += (size_t)N1 * CDIM * 4;
    float* sm  = (float*)(w + off); off += (size_t)N1 * CDIM * 4;
    float* tm  = (float*)(w + off); off += (size_t)N0 * CDIM * 4;
    float* pl0 = (float*)(w + off); off += (size_t)N0 * 4;
    float* pr0 = (float*)(w + off); off += (size_t)N0 * 4;
    float* pl1 = (float*)(w + off); off += (size_t)N1 * 4;
    float* pr1 = (float*)(w + off); off += (size_t)N1 * 4;
    float* pls = (float*)(w + off); off += (size_t)N1 * 4;   // p_s = sm @ a_ns[:C]
    float* prs = (float*)(w + off); off += (size_t)N1 * 4;   // scratch
    float* plt = (float*)(w + off); off += (size_t)N0 * 4;   // scratch
    float* prt = (float*)(w + off); off += (size_t)N0 * 4;   // p_t = tm @ a_ns[C:]
    // cursors: contiguous concatenation -> one global scan gives absolute csr offsets
    int* curAll = (int*)(w + off);
    int* cur0 = curAll;            // N0
    int* cur1 = cur0 + N0;         // N1
    int* curT = cur1 + N1;         // N0
    int* curS = curT + N0;         // N1
    const int Ntot = N0 + N1 + N0 + N1;
    off += (size_t)Ntot * 4;
    int* part = (int*)(w + off); off += 1024 * 4;   // scan partials
    int2* csrAll = (int2*)(w + off); off += ((size_t)E0 + E1 + 2 * (size_t)E01) * 8;
    (void)ws_size; (void)n_in; (void)out_size;

    const int base0 = 0;
    const int base1 = E0;
    const int baseT = E0 + E1;
    const int baseS = E0 + E1 + E01;

    dim3 blk(256);

    // ---- CSR build: count -> global scan ----
    hipMemsetAsync(curAll, 0, (size_t)Ntot * 4, stream);
    count_kernel<<<(E0 + 255) / 256, blk, 0, stream>>>(adj0, cur0, E0);
    count_kernel<<<(E1 + 255) / 256, blk, 0, stream>>>(adj1, cur1, E1);
    count_kernel<<<(E01 + 255) / 256, blk, 0, stream>>>(inct, curT, E01);
    count_kernel<<<(E01 + 255) / 256, blk, 0, stream>>>(incs, curS, E01);

    int nCh = (Ntot + SCAN_CHUNK - 1) / SCAN_CHUNK;
    scan_partials<<<nCh, blk, 0, stream>>>(curAll, part, Ntot);
    scan_small<<<1, blk, 0, stream>>>(part, nCh);
    scan_apply<<<nCh, blk, 0, stream>>>(curAll, part, Ntot);

    // ---- dense projections (tiled, shuffle-free) ----
    gemm64x2_tiled<<<(N0 + 63) / 64, blk, 0, stream>>>(x0, W0, m0, Wt, tm, N0);
    gemm64x2_tiled<<<(N1 + 63) / 64, blk, 0, stream>>>(x1, W1, m1, Ws, sm, N1);

    // ---- p-pass: per-row dual dot products ----
    ppass_kernel<<<(2 * (N0 + N1) + 255) / 256, blk, 0, stream>>>(
        m0, m1, sm, tm, a0, a1, ans,
        pl0, pr0, pl1, pr1, pls, prs, plt, prt, N0, N1);

    // ---- fills ----
    fill_kernel<<<(E0 + 255) / 256, blk, 0, stream>>>(adj0, adj0 + E0, pl0, pr0, cur0, csrAll, E0);
    fill_kernel<<<(E1 + 255) / 256, blk, 0, stream>>>(adj1, adj1 + E1, pl1, pr1, cur1, csrAll, E1);
    fill_kernel<<<(E01 + 255) / 256, blk, 0, stream>>>(inct, incs, prt, pls, curT, csrAll, E01);
    fill_kernel<<<(E01 + 255) / 256, blk, 0, stream>>>(incs, inct, pls, prt, curS, csrAll, E01);

    // ---- fused pull gathers: out = A/denA + B/denB, single write ----
    gather2_kernel<<<2048, blk, 0, stream>>>(cur0, base0, m0, curT, baseT, sm, csrAll, out0, N0);
    gather2_kernel<<<2048, blk, 0, stream>>>(cur1, base1, m1, curS, baseS, tm, csrAll, out1, N1);

    // ---- passthroughs x_2, x_3, x_4 ----
    hipMemcpyAsync(outp,          x2, (size_t)NP * sizeof(float), hipMemcpyDeviceToDevice, stream);
    hipMemcpyAsync(outp + NP,     x3, (size_t)NP * sizeof(float), hipMemcpyDeviceToDevice, stream);
    hipMemcpyAsync(outp + 2 * NP, x4, (size_t)NP * sizeof(float), hipMemcpyDeviceToDevice, stream);
}